// Round 14
// baseline (347.949 us; speedup 1.0000x reference)
//
#include <hip/hip_runtime.h>

// Problem constants (match reference setup_inputs)
#define NN 100000
#define NE 600000
#define NG 256
#define HID 128
#define BN_EPS 1e-5f

#define SCAN_TILE 1024
#define NTILES ((NN + SCAN_TILE - 1) / SCAN_TILE)  // 98
#define MM_TILES (NN / 32)                          // 3125 (NN % 32 == 0)

typedef __attribute__((ext_vector_type(8))) short short8;
typedef __attribute__((ext_vector_type(4))) float float4v;

// bf16 round-to-nearest-even helpers
__device__ __forceinline__ unsigned short f2bf_rn(float f) {
    unsigned u = __float_as_uint(f);
    unsigned r = u + 0x7FFFu + ((u >> 16) & 1u);
    return (unsigned short)(r >> 16);
}
__device__ __forceinline__ float bf2f(unsigned short h) {
    return __uint_as_float((unsigned)h << 16);
}
__device__ __forceinline__ void unpack8(uint4 u, float* f) {
    f[0] = __uint_as_float(u.x << 16); f[1] = __uint_as_float(u.x & 0xFFFF0000u);
    f[2] = __uint_as_float(u.y << 16); f[3] = __uint_as_float(u.y & 0xFFFF0000u);
    f[4] = __uint_as_float(u.z << 16); f[5] = __uint_as_float(u.z & 0xFFFF0000u);
    f[6] = __uint_as_float(u.w << 16); f[7] = __uint_as_float(u.w & 0xFFFF0000u);
}

// ---------------- histogram of dst (in-degree) ----------------

__global__ __launch_bounds__(256) void hist_kernel(const int* __restrict__ dst, int* __restrict__ cnt) {
    int e = blockIdx.x * blockDim.x + threadIdx.x;
    if (e < NE) atomicAdd(&cnt[dst[e]], 1);
}

// ---------------- 2-level exclusive scan of cnt -> row_start (+ dinv fused) ----------------

__global__ __launch_bounds__(256) void scan_a(const int* __restrict__ cnt, int* __restrict__ rs,
                                              int* __restrict__ tsum, float* __restrict__ dinv) {
    __shared__ int s[256];
    int t = threadIdx.x;
    int base = blockIdx.x * SCAN_TILE;
    int idx = base + t * 4;
    int v0 = (idx + 0 < NN) ? cnt[idx + 0] : 0;
    int v1 = (idx + 1 < NN) ? cnt[idx + 1] : 0;
    int v2 = (idx + 2 < NN) ? cnt[idx + 2] : 0;
    int v3 = (idx + 3 < NN) ? cnt[idx + 3] : 0;
    if (idx + 0 < NN) dinv[idx + 0] = rsqrtf((float)v0 + 1.0f);
    if (idx + 1 < NN) dinv[idx + 1] = rsqrtf((float)v1 + 1.0f);
    if (idx + 2 < NN) dinv[idx + 2] = rsqrtf((float)v2 + 1.0f);
    if (idx + 3 < NN) dinv[idx + 3] = rsqrtf((float)v3 + 1.0f);
    int local = v0 + v1 + v2 + v3;
    s[t] = local;
    __syncthreads();
    for (int off = 1; off < 256; off <<= 1) {
        int x = (t >= off) ? s[t - off] : 0;
        __syncthreads();
        s[t] += x;
        __syncthreads();
    }
    int pre = s[t] - local;  // exclusive prefix within tile
    if (t == 255) tsum[blockIdx.x] = s[255];
    if (idx + 0 < NN) rs[idx + 0] = pre; pre += v0;
    if (idx + 1 < NN) rs[idx + 1] = pre; pre += v1;
    if (idx + 2 < NN) rs[idx + 2] = pre; pre += v2;
    if (idx + 3 < NN) rs[idx + 3] = pre;
}

__global__ __launch_bounds__(128) void scan_b(int* __restrict__ tsum) {
    __shared__ int s[128];
    int t = threadIdx.x;
    int v = (t < NTILES) ? tsum[t] : 0;
    s[t] = v;
    __syncthreads();
    for (int off = 1; off < 128; off <<= 1) {
        int x = (t >= off) ? s[t - off] : 0;
        __syncthreads();
        s[t] += x;
        __syncthreads();
    }
    if (t < NTILES) tsum[t] = s[t] - v;  // exclusive
}

__global__ __launch_bounds__(256) void scan_c(int* __restrict__ rs, const int* __restrict__ tsum,
                                              int* __restrict__ cursor) {
    int t = threadIdx.x;
    int base = blockIdx.x * SCAN_TILE;
    int off = tsum[blockIdx.x];
    for (int k = 0; k < 4; k++) {
        int idx = base + t * 4 + k;
        if (idx < NN) {
            int v = rs[idx] + off;
            rs[idx] = v;
            cursor[idx] = v;
        }
    }
    if (blockIdx.x == 0 && t == 0) rs[NN] = NE;
}

// ---------------- bucket edges by dst + prep (fused, independent halves) ----------------
// blocks [0, NB): bucket (esrc only; weights on the fly later)
// blocks [NB, NB+64): split W1/W2 into bf16 hi/lo transposed
// block NB+64: pocket MLP

__global__ __launch_bounds__(256) void bucket_prep_kernel(const int* __restrict__ src, const int* __restrict__ dst,
                                                          int* __restrict__ cursor, int* __restrict__ esrc,
                                                          const float* __restrict__ W1, const float* __restrict__ W2,
                                                          unsigned short* __restrict__ w1hi, unsigned short* __restrict__ w1lo,
                                                          unsigned short* __restrict__ w2hi, unsigned short* __restrict__ w2lo,
                                                          const float* __restrict__ pocket,
                                                          const float* __restrict__ pw1, const float* __restrict__ pb1,
                                                          const float* __restrict__ pw2, const float* __restrict__ pb2,
                                                          float* __restrict__ pv, int nb) {
    if ((int)blockIdx.x < nb) {
        int e = blockIdx.x * 256 + threadIdx.x;
        if (e < NE) {
            int pos = atomicAdd(&cursor[dst[e]], 1);
            esrc[pos] = src[e];
        }
    } else if ((int)blockIdx.x < nb + 64) {
        int t = (blockIdx.x - nb) * 256 + threadIdx.x;
        int k = t >> 7, n = t & 127;      // W[k][n]
        int to = n * HID + k;             // Wt[n][k]
        float v1 = W1[t];
        unsigned short h1 = f2bf_rn(v1);
        w1hi[to] = h1;
        w1lo[to] = f2bf_rn(v1 - bf2f(h1));
        float v2 = W2[t];
        unsigned short h2 = f2bf_rn(v2);
        w2hi[to] = h2;
        w2lo[to] = f2bf_rn(v2 - bf2f(h2));
    } else {
        __shared__ float t1[64];
        int j = threadIdx.x;
        if (j < 64) {
            float acc = pb1[j];
            for (int k = 0; k < 28; k++) acc = fmaf(pocket[k], pw1[k * 64 + j], acc);
            t1[j] = fmaxf(acc, 0.f);
        }
        __syncthreads();
        if (j < 64) {
            float acc2 = pb2[j];
            for (int k = 0; k < 64; k++) acc2 = fmaf(t1[k], pw2[k * 64 + j], acc2);
            pv[j] = acc2;
        }
    }
}

// ---------------- layer 0 fully fused: agg(x) -> @W0 -> BN -> ReLU -> bf16 ----------------
// 32 nodes per block iter. Phase 1: 256 thr = 32 nodes x 8 lanes aggregate x
// into LDS (7 floats/node; weights dinv*dinv on the fly). Phase 2: 256 thr =
// 8 nodes x 32 feature-quads, 4 iterations; coalesced ushort4 stores.
// W0 footprint is only 28 regs/thread -> no occupancy cliff (unlike R3's 128).

__global__ __launch_bounds__(256) void l0_fused(const float* __restrict__ x,
                                                const int* __restrict__ rs,
                                                const int* __restrict__ esrc,
                                                const float* __restrict__ dinv,
                                                const float* __restrict__ W,
                                                const float* __restrict__ b,
                                                const float* __restrict__ gamma,
                                                const float* __restrict__ beta,
                                                const float* __restrict__ mean,
                                                const float* __restrict__ var,
                                                unsigned short* __restrict__ ohi) {
    int c4 = threadIdx.x & 31;   // phase-2 feature quad
    int r8 = threadIdx.x >> 5;   // phase-2 node-within-8
    float w[7][4];
#pragma unroll
    for (int k = 0; k < 7; k++)
#pragma unroll
        for (int i = 0; i < 4; i++) w[k][i] = W[k * HID + c4 * 4 + i];
    float4 bb = ((const float4*)b)[c4];
    float4 ga = ((const float4*)gamma)[c4];
    float4 be = ((const float4*)beta)[c4];
    float4 me = ((const float4*)mean)[c4];
    float4 va = ((const float4*)var)[c4];
    float4 sc;
    sc.x = ga.x * rsqrtf(va.x + BN_EPS);
    sc.y = ga.y * rsqrtf(va.y + BN_EPS);
    sc.z = ga.z * rsqrtf(va.z + BN_EPS);
    sc.w = ga.w * rsqrtf(va.w + BN_EPS);
    int m = threadIdx.x >> 3, f = threadIdx.x & 7;  // phase-1 mapping
    __shared__ float s[32][8];
    for (int n0 = blockIdx.x * 32; n0 < NN; n0 += gridDim.x * 32) {
        __syncthreads();
        // phase 1: aggregate x for node n0+m, feature f (NN % 32 == 0)
        float acc = 0.f;
        int n = n0 + m;
        if (f < 7) {
            float di = dinv[n];
            acc = x[n * 7 + f] * di * di;
            int e0 = rs[n], e1 = rs[n + 1];
            int e = e0;
            for (; e + 1 < e1; e += 2) {
                int s0 = esrc[e], s1 = esrc[e + 1];
                float w0 = dinv[s0] * di, w1 = dinv[s1] * di;
                float a0 = x[s0 * 7 + f];
                float a1 = x[s1 * 7 + f];
                acc = fmaf(a0, w0, acc);
                acc = fmaf(a1, w1, acc);
            }
            if (e < e1) {
                int s0 = esrc[e];
                acc = fmaf(x[s0 * 7 + f], dinv[s0] * di, acc);
            }
        }
        s[m][f] = acc;
        __syncthreads();
        // phase 2: transform 32 nodes, 8 per iteration
#pragma unroll
        for (int g = 0; g < 4; g++) {
            int m2 = g * 8 + r8;
            float o0 = bb.x, o1 = bb.y, o2 = bb.z, o3 = bb.w;
#pragma unroll
            for (int k = 0; k < 7; k++) {
                float xv = s[m2][k];
                o0 = fmaf(xv, w[k][0], o0);
                o1 = fmaf(xv, w[k][1], o1);
                o2 = fmaf(xv, w[k][2], o2);
                o3 = fmaf(xv, w[k][3], o3);
            }
            ushort4 hi4;
            hi4.x = f2bf_rn(fmaxf(fmaf(o0 - me.x, sc.x, be.x), 0.f));
            hi4.y = f2bf_rn(fmaxf(fmaf(o1 - me.y, sc.y, be.y), 0.f));
            hi4.z = f2bf_rn(fmaxf(fmaf(o2 - me.z, sc.z, be.z), 0.f));
            hi4.w = f2bf_rn(fmaxf(fmaf(o3 - me.w, sc.w, be.w), 0.f));
            *(ushort4*)(ohi + (size_t)(n0 + m2) * HID + c4 * 4) = hi4;
        }
    }
}

// ---------------- layers 1/2 matmul via MFMA ----------------
// Persistent blocks (<=2 tiles each); W hi/lo fragments register-resident;
// next tile's A fragments prefetched during compute.

__global__ __launch_bounds__(256) void mm_mfma(const unsigned short* __restrict__ A,
                                               const unsigned short* __restrict__ Whi,
                                               const unsigned short* __restrict__ Wlo,
                                               unsigned short* __restrict__ out) {
    int wave = threadIdx.x >> 6;
    int lane = threadIdx.x & 63;
    int mrow = lane & 15;
    int quad = lane >> 4;
    int n0 = wave * 32;

    short8 bh[2][4], bl[2][4];
#pragma unroll
    for (int ct = 0; ct < 2; ct++) {
#pragma unroll
        for (int kc = 0; kc < 4; kc++) {
            size_t off = (size_t)(n0 + ct * 16 + mrow) * HID + kc * 32 + quad * 8;
            bh[ct][kc] = *(const short8*)(Whi + off);
            bl[ct][kc] = *(const short8*)(Wlo + off);
        }
    }

    int tile = blockIdx.x;
    if (tile >= MM_TILES) return;

    short8 ah[2][4];
#pragma unroll
    for (int rt = 0; rt < 2; rt++)
#pragma unroll
        for (int kc = 0; kc < 4; kc++)
            ah[rt][kc] = *(const short8*)(A + (size_t)(tile * 32 + rt * 16 + mrow) * HID + kc * 32 + quad * 8);

    for (;;) {
        int nt = tile + gridDim.x;
        bool has_next = nt < MM_TILES;
        short8 an[2][4];
        if (has_next) {
#pragma unroll
            for (int rt = 0; rt < 2; rt++)
#pragma unroll
                for (int kc = 0; kc < 4; kc++)
                    an[rt][kc] = *(const short8*)(A + (size_t)(nt * 32 + rt * 16 + mrow) * HID + kc * 32 + quad * 8);
        }

        float4v acc[2][2];
#pragma unroll
        for (int rt = 0; rt < 2; rt++)
#pragma unroll
            for (int ct = 0; ct < 2; ct++) {
                acc[rt][ct].x = 0.f; acc[rt][ct].y = 0.f;
                acc[rt][ct].z = 0.f; acc[rt][ct].w = 0.f;
            }

#pragma unroll
        for (int kc = 0; kc < 4; kc++)
#pragma unroll
            for (int rt = 0; rt < 2; rt++)
#pragma unroll
                for (int ct = 0; ct < 2; ct++) {
                    acc[rt][ct] = __builtin_amdgcn_mfma_f32_16x16x32_bf16(ah[rt][kc], bh[ct][kc], acc[rt][ct], 0, 0, 0);
                    acc[rt][ct] = __builtin_amdgcn_mfma_f32_16x16x32_bf16(ah[rt][kc], bl[ct][kc], acc[rt][ct], 0, 0, 0);
                }

        int m0 = tile * 32;
#pragma unroll
        for (int rt = 0; rt < 2; rt++)
#pragma unroll
            for (int ct = 0; ct < 2; ct++) {
                int col = n0 + ct * 16 + mrow;
#pragma unroll
                for (int r = 0; r < 4; r++) {
                    int row = m0 + rt * 16 + quad * 4 + r;
                    out[(size_t)row * HID + col] = f2bf_rn(acc[rt][ct][r]);
                }
            }

        if (!has_next) break;
#pragma unroll
        for (int rt = 0; rt < 2; rt++)
#pragma unroll
            for (int kc = 0; kc < 4; kc++) ah[rt][kc] = an[rt][kc];
        tile = nt;
    }
}

// ---------------- gather-aggregate + self-loop + bias + BN + ReLU -> bf16 ----------------
// 16 lanes/node, uint4 gathers, 4x unroll; weights dinv[s]*dinv[n] on the fly.

__global__ __launch_bounds__(256) void gather_bn(const unsigned short* __restrict__ hl,
                                                 const int* __restrict__ rs,
                                                 const int* __restrict__ esrc,
                                                 const float* __restrict__ dinv,
                                                 const float* __restrict__ b,
                                                 const float* __restrict__ gamma,
                                                 const float* __restrict__ beta,
                                                 const float* __restrict__ mean,
                                                 const float* __restrict__ var,
                                                 unsigned short* __restrict__ ohi) {
    int t = blockIdx.x * blockDim.x + threadIdx.x;
    int lane = t & 15;          // 16-B chunk within 256-B row (8 features)
    int n = t >> 4;
    if (n >= NN) return;
    const uint4* hlv = (const uint4*)hl;  // 16 uint4 per row
    float di = dinv[n];
    float dsq = di * di;

    float acc[8], v[8];
    {
        uint4 sv = hlv[(size_t)n * 16 + lane];
        unpack8(sv, v);
        float4 bA = ((const float4*)b)[lane * 2];
        float4 bB = ((const float4*)b)[lane * 2 + 1];
        acc[0] = fmaf(v[0], dsq, bA.x); acc[1] = fmaf(v[1], dsq, bA.y);
        acc[2] = fmaf(v[2], dsq, bA.z); acc[3] = fmaf(v[3], dsq, bA.w);
        acc[4] = fmaf(v[4], dsq, bB.x); acc[5] = fmaf(v[5], dsq, bB.y);
        acc[6] = fmaf(v[6], dsq, bB.z); acc[7] = fmaf(v[7], dsq, bB.w);
    }

    int e0 = rs[n], e1 = rs[n + 1];
    int e = e0;
    for (; e + 3 < e1; e += 4) {
        int s0 = esrc[e], s1 = esrc[e + 1], s2 = esrc[e + 2], s3 = esrc[e + 3];
        float w0 = dinv[s0] * di, w1 = dinv[s1] * di;
        float w2 = dinv[s2] * di, w3 = dinv[s3] * di;
        uint4 u0 = hlv[(size_t)s0 * 16 + lane];
        uint4 u1 = hlv[(size_t)s1 * 16 + lane];
        uint4 u2 = hlv[(size_t)s2 * 16 + lane];
        uint4 u3 = hlv[(size_t)s3 * 16 + lane];
        unpack8(u0, v);
#pragma unroll
        for (int i = 0; i < 8; i++) acc[i] = fmaf(v[i], w0, acc[i]);
        unpack8(u1, v);
#pragma unroll
        for (int i = 0; i < 8; i++) acc[i] = fmaf(v[i], w1, acc[i]);
        unpack8(u2, v);
#pragma unroll
        for (int i = 0; i < 8; i++) acc[i] = fmaf(v[i], w2, acc[i]);
        unpack8(u3, v);
#pragma unroll
        for (int i = 0; i < 8; i++) acc[i] = fmaf(v[i], w3, acc[i]);
    }
    for (; e < e1; e++) {
        int s0 = esrc[e];
        float w0 = dinv[s0] * di;
        uint4 u0 = hlv[(size_t)s0 * 16 + lane];
        unpack8(u0, v);
#pragma unroll
        for (int i = 0; i < 8; i++) acc[i] = fmaf(v[i], w0, acc[i]);
    }

    float4 gA = ((const float4*)gamma)[lane * 2], gB = ((const float4*)gamma)[lane * 2 + 1];
    float4 eA = ((const float4*)beta)[lane * 2],  eB = ((const float4*)beta)[lane * 2 + 1];
    float4 mA = ((const float4*)mean)[lane * 2],  mB = ((const float4*)mean)[lane * 2 + 1];
    float4 vA = ((const float4*)var)[lane * 2],   vB = ((const float4*)var)[lane * 2 + 1];
    float o[8];
    o[0] = fmaxf(fmaf(acc[0] - mA.x, gA.x * rsqrtf(vA.x + BN_EPS), eA.x), 0.f);
    o[1] = fmaxf(fmaf(acc[1] - mA.y, gA.y * rsqrtf(vA.y + BN_EPS), eA.y), 0.f);
    o[2] = fmaxf(fmaf(acc[2] - mA.z, gA.z * rsqrtf(vA.z + BN_EPS), eA.z), 0.f);
    o[3] = fmaxf(fmaf(acc[3] - mA.w, gA.w * rsqrtf(vA.w + BN_EPS), eA.w), 0.f);
    o[4] = fmaxf(fmaf(acc[4] - mB.x, gB.x * rsqrtf(vB.x + BN_EPS), eB.x), 0.f);
    o[5] = fmaxf(fmaf(acc[5] - mB.y, gB.y * rsqrtf(vB.y + BN_EPS), eB.y), 0.f);
    o[6] = fmaxf(fmaf(acc[6] - mB.z, gB.z * rsqrtf(vB.z + BN_EPS), eB.z), 0.f);
    o[7] = fmaxf(fmaf(acc[7] - mB.w, gB.w * rsqrtf(vB.w + BN_EPS), eB.w), 0.f);

    uint4 p;
    p.x = (unsigned)f2bf_rn(o[0]) | ((unsigned)f2bf_rn(o[1]) << 16);
    p.y = (unsigned)f2bf_rn(o[2]) | ((unsigned)f2bf_rn(o[3]) << 16);
    p.z = (unsigned)f2bf_rn(o[4]) | ((unsigned)f2bf_rn(o[5]) << 16);
    p.w = (unsigned)f2bf_rn(o[6]) | ((unsigned)f2bf_rn(o[7]) << 16);
    ((uint4*)ohi)[(size_t)n * 16 + lane] = p;
}

// ---------------- fused global mean pool + classifier (bf16 input) ----------------

__global__ __launch_bounds__(1024) void poolcls_kernel(const unsigned short* __restrict__ h,
                                                       const int* __restrict__ batch,
                                                       const float* __restrict__ pv,
                                                       const float* __restrict__ cw1,
                                                       const float* __restrict__ cb1,
                                                       const float* __restrict__ cw2,
                                                       const float* __restrict__ cb2,
                                                       float* __restrict__ out) {
    int g = blockIdx.x;
    int lane = threadIdx.x & 31;   // 8-B chunk (4 features) within 256-B row
    int row = threadIdx.x >> 5;    // 0..31
    __shared__ int se[2];
    __shared__ float emb[192];
    __shared__ float hid[96];
    if (threadIdx.x < 2) {
        int target = g + threadIdx.x;
        int lo = 0, hi = NN;
        while (lo < hi) {
            int mid = (lo + hi) >> 1;
            if (batch[mid] < target) lo = mid + 1; else hi = mid;
        }
        se[threadIdx.x] = lo;
    }
    if (threadIdx.x < 64) emb[128 + threadIdx.x] = pv[threadIdx.x];
    __syncthreads();
    int start = se[0], end = se[1];
    const uint2* h2 = (const uint2*)h;  // 32 uint2 per row
    float4 acc = make_float4(0.f, 0.f, 0.f, 0.f);
    for (int n = start + row; n < end; n += 32) {
        uint2 u = h2[(size_t)n * 32 + lane];
        acc.x += __uint_as_float(u.x << 16);
        acc.y += __uint_as_float(u.x & 0xFFFF0000u);
        acc.z += __uint_as_float(u.y << 16);
        acc.w += __uint_as_float(u.y & 0xFFFF0000u);
    }
    __shared__ float4 part[32][32];
    part[row][lane] = acc;
    __syncthreads();
#pragma unroll
    for (int off = 16; off >= 1; off >>= 1) {
        if (row < off) {
            float4 a = part[row][lane];
            float4 c = part[row + off][lane];
            a.x += c.x; a.y += c.y; a.z += c.z; a.w += c.w;
            part[row][lane] = a;
        }
        __syncthreads();
    }
    if (row == 0) {
        float inv = 1.0f / fmaxf((float)(end - start), 1.0f);
        float4 a = part[0][lane];
        a.x *= inv; a.y *= inv; a.z *= inv; a.w *= inv;
        ((float4*)emb)[lane] = a;
    }
    __syncthreads();
    int j = threadIdx.x;
    if (j < 96) {
        float a = cb1[j];
        for (int k = 0; k < 192; k++) a = fmaf(emb[k], cw1[k * 96 + j], a);
        hid[j] = fmaxf(a, 0.f) * cw2[j];
    }
    __syncthreads();
    if (j == 0) {
        float s = cb2[0];
        for (int k = 0; k < 96; k++) s += hid[k];
        out[g] = s;
    }
}

extern "C" void kernel_launch(void* const* d_in, const int* in_sizes, int n_in,
                              void* d_out, int out_size, void* d_ws, size_t ws_size,
                              hipStream_t stream) {
    const float* x        = (const float*)d_in[0];
    const int*   eidx     = (const int*)d_in[1];
    const int*   batch    = (const int*)d_in[2];
    const float* pocket   = (const float*)d_in[3];
    const float* W0 = (const float*)d_in[4];
    const float* b0 = (const float*)d_in[5];
    const float* W1 = (const float*)d_in[6];
    const float* b1 = (const float*)d_in[7];
    const float* W2 = (const float*)d_in[8];
    const float* b2 = (const float*)d_in[9];
    const float* bn_gamma = (const float*)d_in[10];
    const float* bn_beta  = (const float*)d_in[11];
    const float* bn_mean  = (const float*)d_in[12];
    const float* bn_var   = (const float*)d_in[13];
    const float* pw1 = (const float*)d_in[14]; const float* pb1 = (const float*)d_in[15];
    const float* pw2 = (const float*)d_in[16]; const float* pb2 = (const float*)d_in[17];
    const float* cw1 = (const float*)d_in[18]; const float* cb1 = (const float*)d_in[19];
    const float* cw2 = (const float*)d_in[20]; const float* cb2 = (const float*)d_in[21];
    float* out = (float*)d_out;

    // Workspace layout (4-byte units):
    float* ws   = (float*)d_ws;
    float* dinv = ws;                                   // NN
    int*   cnt  = (int*)(ws + NN);                      // NN (hist, then cursor)
    int*   rs   = cnt + NN;                             // NN+1
    int*   tsum = rs + NN + 1;                          // 128
    int*   esrc = tsum + 128;                           // NE
    unsigned short* w1hi = (unsigned short*)(esrc + NE);  // 16384 each
    unsigned short* w1lo = w1hi + HID * HID;
    unsigned short* w2hi = w1lo + HID * HID;
    unsigned short* w2lo = w2hi + HID * HID;
    size_t head = (size_t)NN * 2 + (NN + 1) + 128 + NE + (4 * HID * HID) / 2;
    head = (head + 3) & ~(size_t)3;                     // 16B align
    unsigned short* A = (unsigned short*)(ws + head);   // NN*HID ushort (bf16)
    unsigned short* B = A + (size_t)NN * HID;           // NN*HID ushort (bf16)
    float* pv   = (float*)(B + (size_t)NN * HID);       // 64

    const int* srcp = eidx;
    const int* dstp = eidx + NE;

    const int NB = (NE + 255) / 256;  // bucket blocks

    // ---- build CSR (by dst) + dinv; split W1/W2 + pocket ----
    hipMemsetAsync(cnt, 0, NN * sizeof(int), stream);
    hist_kernel<<<NB, 256, 0, stream>>>(dstp, cnt);
    scan_a<<<NTILES, 256, 0, stream>>>(cnt, rs, tsum, dinv);
    scan_b<<<1, 128, 0, stream>>>(tsum);
    scan_c<<<NTILES, 256, 0, stream>>>(rs, tsum, cnt);  // cnt becomes cursor
    bucket_prep_kernel<<<NB + 65, 256, 0, stream>>>(srcp, dstp, cnt, esrc,
                                                    W1, W2, w1hi, w1lo, w2hi, w2lo,
                                                    pocket, pw1, pb1, pw2, pb2, pv, NB);

    // ---- layer 0 fused: agg(x) -> @W0 -> BN -> ReLU -> bf16 plane A ----
    l0_fused<<<1024, 256, 0, stream>>>(x, rs, esrc, dinv, W0, b0,
                                       bn_gamma + 0 * HID, bn_beta + 0 * HID,
                                       bn_mean + 0 * HID, bn_var + 0 * HID, A);

    const int MM_BLOCKS = (MM_TILES + 1) / 2;  // 1563: <=2 tiles/block, balanced
    const int GA_BLOCKS = (NN * 16 + 255) / 256;

    // ---- layer 1: A -> B(hl) -> A(h) ----
    mm_mfma<<<MM_BLOCKS, 256, 0, stream>>>(A, w1hi, w1lo, B);
    gather_bn<<<GA_BLOCKS, 256, 0, stream>>>(
        B, rs, esrc, dinv, b1,
        bn_gamma + 1 * HID, bn_beta + 1 * HID, bn_mean + 1 * HID, bn_var + 1 * HID, A);
    // ---- layer 2: A -> B(hl) -> A(h) ----
    mm_mfma<<<MM_BLOCKS, 256, 0, stream>>>(A, w2hi, w2lo, B);
    gather_bn<<<GA_BLOCKS, 256, 0, stream>>>(
        B, rs, esrc, dinv, b2,
        bn_gamma + 2 * HID, bn_beta + 2 * HID, bn_mean + 2 * HID, bn_var + 2 * HID, A);

    // fused pool + classifier (bf16 h)
    poolcls_kernel<<<NG, 1024, 0, stream>>>(A, batch, pv, cw1, cb1, cw2, cb2, out);
}

// Round 15
// 332.858 us; speedup vs baseline: 1.0453x; 1.0453x over previous
//
#include <hip/hip_runtime.h>

// Problem constants (match reference setup_inputs)
#define NN 100000
#define NE 600000
#define NG 256
#define HID 128
#define BN_EPS 1e-5f

#define SCAN_TILE 1024
#define NTILES ((NN + SCAN_TILE - 1) / SCAN_TILE)  // 98
#define MM_TILES (NN / 32)                          // 3125 (NN % 32 == 0)

typedef __attribute__((ext_vector_type(8))) short short8;
typedef __attribute__((ext_vector_type(4))) float float4v;

// bf16 round-to-nearest-even helpers
__device__ __forceinline__ unsigned short f2bf_rn(float f) {
    unsigned u = __float_as_uint(f);
    unsigned r = u + 0x7FFFu + ((u >> 16) & 1u);
    return (unsigned short)(r >> 16);
}
__device__ __forceinline__ float bf2f(unsigned short h) {
    return __uint_as_float((unsigned)h << 16);
}
__device__ __forceinline__ void unpack8(uint4 u, float* f) {
    f[0] = __uint_as_float(u.x << 16); f[1] = __uint_as_float(u.x & 0xFFFF0000u);
    f[2] = __uint_as_float(u.y << 16); f[3] = __uint_as_float(u.y & 0xFFFF0000u);
    f[4] = __uint_as_float(u.z << 16); f[5] = __uint_as_float(u.z & 0xFFFF0000u);
    f[6] = __uint_as_float(u.w << 16); f[7] = __uint_as_float(u.w & 0xFFFF0000u);
}

// ---------------- histogram of dst (in-degree) ----------------

__global__ __launch_bounds__(256) void hist_kernel(const int* __restrict__ dst, int* __restrict__ cnt) {
    int e = blockIdx.x * blockDim.x + threadIdx.x;
    if (e < NE) atomicAdd(&cnt[dst[e]], 1);
}

// ---------------- 2-level exclusive scan of cnt -> row_start (+ dinv fused) ----------------

__global__ __launch_bounds__(256) void scan_a(const int* __restrict__ cnt, int* __restrict__ rs,
                                              int* __restrict__ tsum, float* __restrict__ dinv) {
    __shared__ int s[256];
    int t = threadIdx.x;
    int base = blockIdx.x * SCAN_TILE;
    int idx = base + t * 4;
    int v0 = (idx + 0 < NN) ? cnt[idx + 0] : 0;
    int v1 = (idx + 1 < NN) ? cnt[idx + 1] : 0;
    int v2 = (idx + 2 < NN) ? cnt[idx + 2] : 0;
    int v3 = (idx + 3 < NN) ? cnt[idx + 3] : 0;
    if (idx + 0 < NN) dinv[idx + 0] = rsqrtf((float)v0 + 1.0f);
    if (idx + 1 < NN) dinv[idx + 1] = rsqrtf((float)v1 + 1.0f);
    if (idx + 2 < NN) dinv[idx + 2] = rsqrtf((float)v2 + 1.0f);
    if (idx + 3 < NN) dinv[idx + 3] = rsqrtf((float)v3 + 1.0f);
    int local = v0 + v1 + v2 + v3;
    s[t] = local;
    __syncthreads();
    for (int off = 1; off < 256; off <<= 1) {
        int x = (t >= off) ? s[t - off] : 0;
        __syncthreads();
        s[t] += x;
        __syncthreads();
    }
    int pre = s[t] - local;  // exclusive prefix within tile
    if (t == 255) tsum[blockIdx.x] = s[255];
    if (idx + 0 < NN) rs[idx + 0] = pre; pre += v0;
    if (idx + 1 < NN) rs[idx + 1] = pre; pre += v1;
    if (idx + 2 < NN) rs[idx + 2] = pre; pre += v2;
    if (idx + 3 < NN) rs[idx + 3] = pre;
}

__global__ __launch_bounds__(128) void scan_b(int* __restrict__ tsum) {
    __shared__ int s[128];
    int t = threadIdx.x;
    int v = (t < NTILES) ? tsum[t] : 0;
    s[t] = v;
    __syncthreads();
    for (int off = 1; off < 128; off <<= 1) {
        int x = (t >= off) ? s[t - off] : 0;
        __syncthreads();
        s[t] += x;
        __syncthreads();
    }
    if (t < NTILES) tsum[t] = s[t] - v;  // exclusive
}

__global__ __launch_bounds__(256) void scan_c(int* __restrict__ rs, const int* __restrict__ tsum,
                                              int* __restrict__ cursor) {
    int t = threadIdx.x;
    int base = blockIdx.x * SCAN_TILE;
    int off = tsum[blockIdx.x];
    for (int k = 0; k < 4; k++) {
        int idx = base + t * 4 + k;
        if (idx < NN) {
            int v = rs[idx] + off;
            rs[idx] = v;
            cursor[idx] = v;
        }
    }
    if (blockIdx.x == 0 && t == 0) rs[NN] = NE;
}

// ---------------- bucket edges by dst + prep (fused, independent halves) ----------------

__global__ __launch_bounds__(256) void bucket_prep_kernel(const int* __restrict__ src, const int* __restrict__ dst,
                                                          int* __restrict__ cursor, int* __restrict__ esrc,
                                                          const float* __restrict__ W1, const float* __restrict__ W2,
                                                          unsigned short* __restrict__ w1hi, unsigned short* __restrict__ w1lo,
                                                          unsigned short* __restrict__ w2hi, unsigned short* __restrict__ w2lo,
                                                          const float* __restrict__ pocket,
                                                          const float* __restrict__ pw1, const float* __restrict__ pb1,
                                                          const float* __restrict__ pw2, const float* __restrict__ pb2,
                                                          float* __restrict__ pv, int nb) {
    if ((int)blockIdx.x < nb) {
        int e = blockIdx.x * 256 + threadIdx.x;
        if (e < NE) {
            int pos = atomicAdd(&cursor[dst[e]], 1);
            esrc[pos] = src[e];
        }
    } else if ((int)blockIdx.x < nb + 64) {
        int t = (blockIdx.x - nb) * 256 + threadIdx.x;
        int k = t >> 7, n = t & 127;      // W[k][n]
        int to = n * HID + k;             // Wt[n][k]
        float v1 = W1[t];
        unsigned short h1 = f2bf_rn(v1);
        w1hi[to] = h1;
        w1lo[to] = f2bf_rn(v1 - bf2f(h1));
        float v2 = W2[t];
        unsigned short h2 = f2bf_rn(v2);
        w2hi[to] = h2;
        w2lo[to] = f2bf_rn(v2 - bf2f(h2));
    } else {
        __shared__ float t1[64];
        int j = threadIdx.x;
        if (j < 64) {
            float acc = pb1[j];
            for (int k = 0; k < 28; k++) acc = fmaf(pocket[k], pw1[k * 64 + j], acc);
            t1[j] = fmaxf(acc, 0.f);
        }
        __syncthreads();
        if (j < 64) {
            float acc2 = pb2[j];
            for (int k = 0; k < 64; k++) acc2 = fmaf(t1[k], pw2[k * 64 + j], acc2);
            pv[j] = acc2;
        }
    }
}

// ---------------- layer 0 fused: agg(x) -> @W0 -> BN -> ReLU -> bf16 ----------------
// One-shot grid (NN/32 blocks): each block handles exactly 32 nodes — load
// balance via oversubscription (R14's 1024-persistent version serialized
// variable-degree tiles and regressed).

__global__ __launch_bounds__(256) void l0_fused(const float* __restrict__ x,
                                                const int* __restrict__ rs,
                                                const int* __restrict__ esrc,
                                                const float* __restrict__ dinv,
                                                const float* __restrict__ W,
                                                const float* __restrict__ b,
                                                const float* __restrict__ gamma,
                                                const float* __restrict__ beta,
                                                const float* __restrict__ mean,
                                                const float* __restrict__ var,
                                                unsigned short* __restrict__ ohi) {
    int c4 = threadIdx.x & 31;   // phase-2 feature quad
    int r8 = threadIdx.x >> 5;   // phase-2 node-within-8
    float w[7][4];
#pragma unroll
    for (int k = 0; k < 7; k++)
#pragma unroll
        for (int i = 0; i < 4; i++) w[k][i] = W[k * HID + c4 * 4 + i];
    float4 bb = ((const float4*)b)[c4];
    float4 ga = ((const float4*)gamma)[c4];
    float4 be = ((const float4*)beta)[c4];
    float4 me = ((const float4*)mean)[c4];
    float4 va = ((const float4*)var)[c4];
    float4 sc;
    sc.x = ga.x * rsqrtf(va.x + BN_EPS);
    sc.y = ga.y * rsqrtf(va.y + BN_EPS);
    sc.z = ga.z * rsqrtf(va.z + BN_EPS);
    sc.w = ga.w * rsqrtf(va.w + BN_EPS);
    int m = threadIdx.x >> 3, f = threadIdx.x & 7;  // phase-1 mapping
    __shared__ float s[32][8];
    int n0 = blockIdx.x * 32;
    // phase 1: aggregate x for node n0+m, feature f (NN % 32 == 0)
    float acc = 0.f;
    int n = n0 + m;
    if (f < 7) {
        float di = dinv[n];
        acc = x[n * 7 + f] * di * di;
        int e0 = rs[n], e1 = rs[n + 1];
        int e = e0;
        for (; e + 1 < e1; e += 2) {
            int s0 = esrc[e], s1 = esrc[e + 1];
            float w0 = dinv[s0] * di, w1 = dinv[s1] * di;
            float a0 = x[s0 * 7 + f];
            float a1 = x[s1 * 7 + f];
            acc = fmaf(a0, w0, acc);
            acc = fmaf(a1, w1, acc);
        }
        if (e < e1) {
            int s0 = esrc[e];
            acc = fmaf(x[s0 * 7 + f], dinv[s0] * di, acc);
        }
    }
    s[m][f] = acc;
    __syncthreads();
    // phase 2: transform 32 nodes, 8 per iteration
#pragma unroll
    for (int g = 0; g < 4; g++) {
        int m2 = g * 8 + r8;
        float o0 = bb.x, o1 = bb.y, o2 = bb.z, o3 = bb.w;
#pragma unroll
        for (int k = 0; k < 7; k++) {
            float xv = s[m2][k];
            o0 = fmaf(xv, w[k][0], o0);
            o1 = fmaf(xv, w[k][1], o1);
            o2 = fmaf(xv, w[k][2], o2);
            o3 = fmaf(xv, w[k][3], o3);
        }
        ushort4 hi4;
        hi4.x = f2bf_rn(fmaxf(fmaf(o0 - me.x, sc.x, be.x), 0.f));
        hi4.y = f2bf_rn(fmaxf(fmaf(o1 - me.y, sc.y, be.y), 0.f));
        hi4.z = f2bf_rn(fmaxf(fmaf(o2 - me.z, sc.z, be.z), 0.f));
        hi4.w = f2bf_rn(fmaxf(fmaf(o3 - me.w, sc.w, be.w), 0.f));
        *(ushort4*)(ohi + (size_t)(n0 + m2) * HID + c4 * 4) = hi4;
    }
}

// ---------------- layers 1/2 matmul via MFMA ----------------
// Persistent blocks (grid 1024, ~3 tiles each — R13-proven); W hi/lo fragments
// register-resident; next tile's A fragments prefetched during compute.

__global__ __launch_bounds__(256) void mm_mfma(const unsigned short* __restrict__ A,
                                               const unsigned short* __restrict__ Whi,
                                               const unsigned short* __restrict__ Wlo,
                                               unsigned short* __restrict__ out) {
    int wave = threadIdx.x >> 6;
    int lane = threadIdx.x & 63;
    int mrow = lane & 15;
    int quad = lane >> 4;
    int n0 = wave * 32;

    short8 bh[2][4], bl[2][4];
#pragma unroll
    for (int ct = 0; ct < 2; ct++) {
#pragma unroll
        for (int kc = 0; kc < 4; kc++) {
            size_t off = (size_t)(n0 + ct * 16 + mrow) * HID + kc * 32 + quad * 8;
            bh[ct][kc] = *(const short8*)(Whi + off);
            bl[ct][kc] = *(const short8*)(Wlo + off);
        }
    }

    int tile = blockIdx.x;
    if (tile >= MM_TILES) return;

    short8 ah[2][4];
#pragma unroll
    for (int rt = 0; rt < 2; rt++)
#pragma unroll
        for (int kc = 0; kc < 4; kc++)
            ah[rt][kc] = *(const short8*)(A + (size_t)(tile * 32 + rt * 16 + mrow) * HID + kc * 32 + quad * 8);

    for (;;) {
        int nt = tile + gridDim.x;
        bool has_next = nt < MM_TILES;
        short8 an[2][4];
        if (has_next) {
#pragma unroll
            for (int rt = 0; rt < 2; rt++)
#pragma unroll
                for (int kc = 0; kc < 4; kc++)
                    an[rt][kc] = *(const short8*)(A + (size_t)(nt * 32 + rt * 16 + mrow) * HID + kc * 32 + quad * 8);
        }

        float4v acc[2][2];
#pragma unroll
        for (int rt = 0; rt < 2; rt++)
#pragma unroll
            for (int ct = 0; ct < 2; ct++) {
                acc[rt][ct].x = 0.f; acc[rt][ct].y = 0.f;
                acc[rt][ct].z = 0.f; acc[rt][ct].w = 0.f;
            }

#pragma unroll
        for (int kc = 0; kc < 4; kc++)
#pragma unroll
            for (int rt = 0; rt < 2; rt++)
#pragma unroll
                for (int ct = 0; ct < 2; ct++) {
                    acc[rt][ct] = __builtin_amdgcn_mfma_f32_16x16x32_bf16(ah[rt][kc], bh[ct][kc], acc[rt][ct], 0, 0, 0);
                    acc[rt][ct] = __builtin_amdgcn_mfma_f32_16x16x32_bf16(ah[rt][kc], bl[ct][kc], acc[rt][ct], 0, 0, 0);
                }

        int m0 = tile * 32;
#pragma unroll
        for (int rt = 0; rt < 2; rt++)
#pragma unroll
            for (int ct = 0; ct < 2; ct++) {
                int col = n0 + ct * 16 + mrow;
#pragma unroll
                for (int r = 0; r < 4; r++) {
                    int row = m0 + rt * 16 + quad * 4 + r;
                    out[(size_t)row * HID + col] = f2bf_rn(acc[rt][ct][r]);
                }
            }

        if (!has_next) break;
#pragma unroll
        for (int rt = 0; rt < 2; rt++)
#pragma unroll
            for (int kc = 0; kc < 4; kc++) ah[rt][kc] = an[rt][kc];
        tile = nt;
    }
}

// ---------------- gather-aggregate + self-loop + bias + BN + ReLU -> bf16 ----------------
// 16 lanes/node, uint4 gathers, 4x unroll; weights dinv[s]*dinv[n] on the fly.

__global__ __launch_bounds__(256) void gather_bn(const unsigned short* __restrict__ hl,
                                                 const int* __restrict__ rs,
                                                 const int* __restrict__ esrc,
                                                 const float* __restrict__ dinv,
                                                 const float* __restrict__ b,
                                                 const float* __restrict__ gamma,
                                                 const float* __restrict__ beta,
                                                 const float* __restrict__ mean,
                                                 const float* __restrict__ var,
                                                 unsigned short* __restrict__ ohi) {
    int t = blockIdx.x * blockDim.x + threadIdx.x;
    int lane = t & 15;          // 16-B chunk within 256-B row (8 features)
    int n = t >> 4;
    if (n >= NN) return;
    const uint4* hlv = (const uint4*)hl;  // 16 uint4 per row
    float di = dinv[n];
    float dsq = di * di;

    float acc[8], v[8];
    {
        uint4 sv = hlv[(size_t)n * 16 + lane];
        unpack8(sv, v);
        float4 bA = ((const float4*)b)[lane * 2];
        float4 bB = ((const float4*)b)[lane * 2 + 1];
        acc[0] = fmaf(v[0], dsq, bA.x); acc[1] = fmaf(v[1], dsq, bA.y);
        acc[2] = fmaf(v[2], dsq, bA.z); acc[3] = fmaf(v[3], dsq, bA.w);
        acc[4] = fmaf(v[4], dsq, bB.x); acc[5] = fmaf(v[5], dsq, bB.y);
        acc[6] = fmaf(v[6], dsq, bB.z); acc[7] = fmaf(v[7], dsq, bB.w);
    }

    int e0 = rs[n], e1 = rs[n + 1];
    int e = e0;
    for (; e + 3 < e1; e += 4) {
        int s0 = esrc[e], s1 = esrc[e + 1], s2 = esrc[e + 2], s3 = esrc[e + 3];
        float w0 = dinv[s0] * di, w1 = dinv[s1] * di;
        float w2 = dinv[s2] * di, w3 = dinv[s3] * di;
        uint4 u0 = hlv[(size_t)s0 * 16 + lane];
        uint4 u1 = hlv[(size_t)s1 * 16 + lane];
        uint4 u2 = hlv[(size_t)s2 * 16 + lane];
        uint4 u3 = hlv[(size_t)s3 * 16 + lane];
        unpack8(u0, v);
#pragma unroll
        for (int i = 0; i < 8; i++) acc[i] = fmaf(v[i], w0, acc[i]);
        unpack8(u1, v);
#pragma unroll
        for (int i = 0; i < 8; i++) acc[i] = fmaf(v[i], w1, acc[i]);
        unpack8(u2, v);
#pragma unroll
        for (int i = 0; i < 8; i++) acc[i] = fmaf(v[i], w2, acc[i]);
        unpack8(u3, v);
#pragma unroll
        for (int i = 0; i < 8; i++) acc[i] = fmaf(v[i], w3, acc[i]);
    }
    for (; e < e1; e++) {
        int s0 = esrc[e];
        float w0 = dinv[s0] * di;
        uint4 u0 = hlv[(size_t)s0 * 16 + lane];
        unpack8(u0, v);
#pragma unroll
        for (int i = 0; i < 8; i++) acc[i] = fmaf(v[i], w0, acc[i]);
    }

    float4 gA = ((const float4*)gamma)[lane * 2], gB = ((const float4*)gamma)[lane * 2 + 1];
    float4 eA = ((const float4*)beta)[lane * 2],  eB = ((const float4*)beta)[lane * 2 + 1];
    float4 mA = ((const float4*)mean)[lane * 2],  mB = ((const float4*)mean)[lane * 2 + 1];
    float4 vA = ((const float4*)var)[lane * 2],   vB = ((const float4*)var)[lane * 2 + 1];
    float o[8];
    o[0] = fmaxf(fmaf(acc[0] - mA.x, gA.x * rsqrtf(vA.x + BN_EPS), eA.x), 0.f);
    o[1] = fmaxf(fmaf(acc[1] - mA.y, gA.y * rsqrtf(vA.y + BN_EPS), eA.y), 0.f);
    o[2] = fmaxf(fmaf(acc[2] - mA.z, gA.z * rsqrtf(vA.z + BN_EPS), eA.z), 0.f);
    o[3] = fmaxf(fmaf(acc[3] - mA.w, gA.w * rsqrtf(vA.w + BN_EPS), eA.w), 0.f);
    o[4] = fmaxf(fmaf(acc[4] - mB.x, gB.x * rsqrtf(vB.x + BN_EPS), eB.x), 0.f);
    o[5] = fmaxf(fmaf(acc[5] - mB.y, gB.y * rsqrtf(vB.y + BN_EPS), eB.y), 0.f);
    o[6] = fmaxf(fmaf(acc[6] - mB.z, gB.z * rsqrtf(vB.z + BN_EPS), eB.z), 0.f);
    o[7] = fmaxf(fmaf(acc[7] - mB.w, gB.w * rsqrtf(vB.w + BN_EPS), eB.w), 0.f);

    uint4 p;
    p.x = (unsigned)f2bf_rn(o[0]) | ((unsigned)f2bf_rn(o[1]) << 16);
    p.y = (unsigned)f2bf_rn(o[2]) | ((unsigned)f2bf_rn(o[3]) << 16);
    p.z = (unsigned)f2bf_rn(o[4]) | ((unsigned)f2bf_rn(o[5]) << 16);
    p.w = (unsigned)f2bf_rn(o[6]) | ((unsigned)f2bf_rn(o[7]) << 16);
    ((uint4*)ohi)[(size_t)n * 16 + lane] = p;
}

// ---------------- fused global mean pool + classifier (bf16 input) ----------------

__global__ __launch_bounds__(1024) void poolcls_kernel(const unsigned short* __restrict__ h,
                                                       const int* __restrict__ batch,
                                                       const float* __restrict__ pv,
                                                       const float* __restrict__ cw1,
                                                       const float* __restrict__ cb1,
                                                       const float* __restrict__ cw2,
                                                       const float* __restrict__ cb2,
                                                       float* __restrict__ out) {
    int g = blockIdx.x;
    int lane = threadIdx.x & 31;   // 8-B chunk (4 features) within 256-B row
    int row = threadIdx.x >> 5;    // 0..31
    __shared__ int se[2];
    __shared__ float emb[192];
    __shared__ float hid[96];
    if (threadIdx.x < 2) {
        int target = g + threadIdx.x;
        int lo = 0, hi = NN;
        while (lo < hi) {
            int mid = (lo + hi) >> 1;
            if (batch[mid] < target) lo = mid + 1; else hi = mid;
        }
        se[threadIdx.x] = lo;
    }
    if (threadIdx.x < 64) emb[128 + threadIdx.x] = pv[threadIdx.x];
    __syncthreads();
    int start = se[0], end = se[1];
    const uint2* h2 = (const uint2*)h;  // 32 uint2 per row
    float4 acc = make_float4(0.f, 0.f, 0.f, 0.f);
    for (int n = start + row; n < end; n += 32) {
        uint2 u = h2[(size_t)n * 32 + lane];
        acc.x += __uint_as_float(u.x << 16);
        acc.y += __uint_as_float(u.x & 0xFFFF0000u);
        acc.z += __uint_as_float(u.y << 16);
        acc.w += __uint_as_float(u.y & 0xFFFF0000u);
    }
    __shared__ float4 part[32][32];
    part[row][lane] = acc;
    __syncthreads();
#pragma unroll
    for (int off = 16; off >= 1; off >>= 1) {
        if (row < off) {
            float4 a = part[row][lane];
            float4 c = part[row + off][lane];
            a.x += c.x; a.y += c.y; a.z += c.z; a.w += c.w;
            part[row][lane] = a;
        }
        __syncthreads();
    }
    if (row == 0) {
        float inv = 1.0f / fmaxf((float)(end - start), 1.0f);
        float4 a = part[0][lane];
        a.x *= inv; a.y *= inv; a.z *= inv; a.w *= inv;
        ((float4*)emb)[lane] = a;
    }
    __syncthreads();
    int j = threadIdx.x;
    if (j < 96) {
        float a = cb1[j];
        for (int k = 0; k < 192; k++) a = fmaf(emb[k], cw1[k * 96 + j], a);
        hid[j] = fmaxf(a, 0.f) * cw2[j];
    }
    __syncthreads();
    if (j == 0) {
        float s = cb2[0];
        for (int k = 0; k < 96; k++) s += hid[k];
        out[g] = s;
    }
}

extern "C" void kernel_launch(void* const* d_in, const int* in_sizes, int n_in,
                              void* d_out, int out_size, void* d_ws, size_t ws_size,
                              hipStream_t stream) {
    const float* x        = (const float*)d_in[0];
    const int*   eidx     = (const int*)d_in[1];
    const int*   batch    = (const int*)d_in[2];
    const float* pocket   = (const float*)d_in[3];
    const float* W0 = (const float*)d_in[4];
    const float* b0 = (const float*)d_in[5];
    const float* W1 = (const float*)d_in[6];
    const float* b1 = (const float*)d_in[7];
    const float* W2 = (const float*)d_in[8];
    const float* b2 = (const float*)d_in[9];
    const float* bn_gamma = (const float*)d_in[10];
    const float* bn_beta  = (const float*)d_in[11];
    const float* bn_mean  = (const float*)d_in[12];
    const float* bn_var   = (const float*)d_in[13];
    const float* pw1 = (const float*)d_in[14]; const float* pb1 = (const float*)d_in[15];
    const float* pw2 = (const float*)d_in[16]; const float* pb2 = (const float*)d_in[17];
    const float* cw1 = (const float*)d_in[18]; const float* cb1 = (const float*)d_in[19];
    const float* cw2 = (const float*)d_in[20]; const float* cb2 = (const float*)d_in[21];
    float* out = (float*)d_out;

    // Workspace layout (4-byte units):
    float* ws   = (float*)d_ws;
    float* dinv = ws;                                   // NN
    int*   cnt  = (int*)(ws + NN);                      // NN (hist, then cursor)
    int*   rs   = cnt + NN;                             // NN+1
    int*   tsum = rs + NN + 1;                          // 128
    int*   esrc = tsum + 128;                           // NE
    unsigned short* w1hi = (unsigned short*)(esrc + NE);  // 16384 each
    unsigned short* w1lo = w1hi + HID * HID;
    unsigned short* w2hi = w1lo + HID * HID;
    unsigned short* w2lo = w2hi + HID * HID;
    size_t head = (size_t)NN * 2 + (NN + 1) + 128 + NE + (4 * HID * HID) / 2;
    head = (head + 3) & ~(size_t)3;                     // 16B align
    unsigned short* A = (unsigned short*)(ws + head);   // NN*HID ushort (bf16)
    unsigned short* B = A + (size_t)NN * HID;           // NN*HID ushort (bf16)
    float* pv   = (float*)(B + (size_t)NN * HID);       // 64

    const int* srcp = eidx;
    const int* dstp = eidx + NE;

    const int NB = (NE + 255) / 256;  // bucket blocks

    // ---- build CSR (by dst) + dinv; split W1/W2 + pocket ----
    hipMemsetAsync(cnt, 0, NN * sizeof(int), stream);
    hist_kernel<<<NB, 256, 0, stream>>>(dstp, cnt);
    scan_a<<<NTILES, 256, 0, stream>>>(cnt, rs, tsum, dinv);
    scan_b<<<1, 128, 0, stream>>>(tsum);
    scan_c<<<NTILES, 256, 0, stream>>>(rs, tsum, cnt);  // cnt becomes cursor
    bucket_prep_kernel<<<NB + 65, 256, 0, stream>>>(srcp, dstp, cnt, esrc,
                                                    W1, W2, w1hi, w1lo, w2hi, w2lo,
                                                    pocket, pw1, pb1, pw2, pb2, pv, NB);

    // ---- layer 0 fused: agg(x) -> @W0 -> BN -> ReLU -> bf16 plane A ----
    l0_fused<<<MM_TILES, 256, 0, stream>>>(x, rs, esrc, dinv, W0, b0,
                                           bn_gamma + 0 * HID, bn_beta + 0 * HID,
                                           bn_mean + 0 * HID, bn_var + 0 * HID, A);

    const int MM_BLOCKS = 1024;  // persistent, ~3 tiles/block (R13-proven)
    const int GA_BLOCKS = (NN * 16 + 255) / 256;

    // ---- layer 1: A -> B(hl) -> A(h) ----
    mm_mfma<<<MM_BLOCKS, 256, 0, stream>>>(A, w1hi, w1lo, B);
    gather_bn<<<GA_BLOCKS, 256, 0, stream>>>(
        B, rs, esrc, dinv, b1,
        bn_gamma + 1 * HID, bn_beta + 1 * HID, bn_mean + 1 * HID, bn_var + 1 * HID, A);
    // ---- layer 2: A -> B(hl) -> A(h) ----
    mm_mfma<<<MM_BLOCKS, 256, 0, stream>>>(A, w2hi, w2lo, B);
    gather_bn<<<GA_BLOCKS, 256, 0, stream>>>(
        B, rs, esrc, dinv, b2,
        bn_gamma + 2 * HID, bn_beta + 2 * HID, bn_mean + 2 * HID, bn_var + 2 * HID, A);

    // fused pool + classifier (bf16 h)
    poolcls_kernel<<<NG, 1024, 0, stream>>>(A, batch, pv, cw1, cb1, cw2, cb2, out);
}